// Round 3
// baseline (664.270 us; speedup 1.0000x reference)
//
#include <hip/hip_runtime.h>
#include <hip/hip_bf16.h>
#include <math.h>

#define TOKENS 8192
#define Dm 768
#define Fm 3072
#define Em 8

typedef __attribute__((ext_vector_type(8))) short short8v;
typedef __attribute__((ext_vector_type(4))) float f32x4;

__device__ inline short f2b(float f) {
  __hip_bfloat16 h = __float2bfloat16(f);
  return *reinterpret_cast<short*>(&h);
}

__device__ inline void async16(short* lds, const short* g) {
  __builtin_amdgcn_global_load_lds((const __attribute__((address_space(1))) void*)g,
                                   (__attribute__((address_space(3))) void*)lds, 16, 0, 0);
}

// ---------------- x -> bf16 ----------------
__global__ __launch_bounds__(256) void cvt_x_kernel(const float* __restrict__ x,
                                                    short* __restrict__ xb) {
  size_t i = ((size_t)blockIdx.x * 256 + threadIdx.x) * 8;
  float4 a = *(const float4*)(x + i);
  float4 b = *(const float4*)(x + i + 4);
  short8v v;
  v[0] = f2b(a.x); v[1] = f2b(a.y); v[2] = f2b(a.z); v[3] = f2b(a.w);
  v[4] = f2b(b.x); v[5] = f2b(b.y); v[6] = f2b(b.z); v[7] = f2b(b.w);
  *(short8v*)(xb + i) = v;
}

// ------------- transpose + convert: in f32 [R][C] -> out bf16 [C][R], per expert (z) -------------
__global__ __launch_bounds__(256) void cvt_tr_kernel(const float* __restrict__ in,
                                                     short* __restrict__ out, int R, int C) {
  __shared__ short tile[64][68];
  size_t eoff = (size_t)blockIdx.z * R * C;
  const float* inp = in + eoff;
  short* outp = out + eoff;
  int tc = blockIdx.x * 64, tr = blockIdx.y * 64;
  {
    int row = threadIdx.x >> 2;         // 0..63
    int cch = (threadIdx.x & 3) * 16;   // 0,16,32,48
    const float* src = inp + (size_t)(tr + row) * C + tc + cch;
    #pragma unroll
    for (int q = 0; q < 4; q++) {
      float4 v = *(const float4*)(src + q * 4);
      tile[row][cch + q * 4 + 0] = f2b(v.x);
      tile[row][cch + q * 4 + 1] = f2b(v.y);
      tile[row][cch + q * 4 + 2] = f2b(v.z);
      tile[row][cch + q * 4 + 3] = f2b(v.w);
    }
  }
  __syncthreads();
  {
    int c = threadIdx.x >> 2;           // out row (global col)
    int rch = (threadIdx.x & 3) * 16;
    short tmp[16];
    #pragma unroll
    for (int i = 0; i < 16; i++) tmp[i] = tile[rch + i][c];
    short* dst = outp + (size_t)(tc + c) * R + tr + rch;
    *(short8v*)(dst) = *(short8v*)(tmp);
    *(short8v*)(dst + 8) = *(short8v*)(tmp + 8);
  }
}

// ---------------- router: top-2 + scatter lists + out init ----------------
__global__ __launch_bounds__(256) void router_kernel(
    const float* __restrict__ x, const float* __restrict__ rw,
    const float* __restrict__ rb, const float* __restrict__ b2,
    float* __restrict__ out, int* __restrict__ cnt,
    int* __restrict__ list, float* __restrict__ wlist) {
  int wave = threadIdx.x >> 6;
  int lane = threadIdx.x & 63;
  int t = blockIdx.x * 4 + wave;
  if (t >= TOKENS) return;
  const float* xr = x + (size_t)t * Dm;
  float acc[Em];
  #pragma unroll
  for (int e = 0; e < Em; e++) acc[e] = 0.f;
  #pragma unroll
  for (int i = 0; i < 12; i++) {
    int d = lane + 64 * i;
    float xv = xr[d];
    const float4* rwp = (const float4*)(rw + (size_t)d * Em);
    float4 a = rwp[0], b = rwp[1];
    acc[0] += xv * a.x; acc[1] += xv * a.y; acc[2] += xv * a.z; acc[3] += xv * a.w;
    acc[4] += xv * b.x; acc[5] += xv * b.y; acc[6] += xv * b.z; acc[7] += xv * b.w;
  }
  #pragma unroll
  for (int e = 0; e < Em; e++) {
    float v = acc[e];
    #pragma unroll
    for (int s = 32; s > 0; s >>= 1) v += __shfl_xor(v, s);
    acc[e] = v + rb[e];
  }
  // top-2 (first-occurrence on ties, matches lax.top_k)
  int i1 = 0; float m1 = acc[0];
  #pragma unroll
  for (int e = 1; e < Em; e++) if (acc[e] > m1) { m1 = acc[e]; i1 = e; }
  int i2 = -1; float m2 = -1e30f;
  #pragma unroll
  for (int e = 0; e < Em; e++) if (e != i1 && acc[e] > m2) { m2 = acc[e]; i2 = e; }
  float tt = expf(m2 - m1);
  float p0 = 1.f / (1.f + tt);
  float p1 = tt / (1.f + tt);
  if (lane == 0) {
    int s0 = atomicAdd(&cnt[i1], 1); list[i1 * TOKENS + s0] = t; wlist[i1 * TOKENS + s0] = p0;
    int s1 = atomicAdd(&cnt[i2], 1); list[i2 * TOKENS + s1] = t; wlist[i2 * TOKENS + s1] = p1;
  }
  const float* b2a = b2 + (size_t)i1 * Dm;
  const float* b2b = b2 + (size_t)i2 * Dm;
  float* orow = out + (size_t)t * Dm;
  #pragma unroll
  for (int i = 0; i < 12; i++) {
    int d = lane + 64 * i;
    orow[d] = p0 * b2a[d] + p1 * b2b[d];
  }
}

__global__ void prefix_kernel(const int* __restrict__ cnt, int* __restrict__ hoffs) {
  if (threadIdx.x == 0) {
    int s = 0;
    for (int e = 0; e < Em; e++) { hoffs[e] = s; s += cnt[e]; }
  }
}

// ---------------- grouped GEMM: MODE 0 = x@w1t (+bias,gelu)->h ; MODE 1 = h@w2t *p -> atomic out ----------------
template <int MODE>
__global__ __launch_bounds__(256) void moe_gemm_kernel(
    const short* __restrict__ Abase, const short* __restrict__ Wt,
    const float* __restrict__ bias, short* __restrict__ Hout,
    float* __restrict__ Out, const int* __restrict__ cnt,
    const int* __restrict__ hoffs, const int* __restrict__ list,
    const float* __restrict__ wlist, int Ndim, int Kdim) {
  int e = blockIdx.z;
  int count = cnt[e];
  int mbase = blockIdx.y * 128;
  if (mbase >= count) return;
  int n0 = blockIdx.x * 128;
  int ho = hoffs[e];

  __shared__ short As[128 * 64];
  __shared__ short Bs[128 * 64];
  __shared__ int rid_s[128];
  __shared__ float w_s[128];

  int tid = threadIdx.x;
  if (tid < 128) {
    int r = mbase + tid;
    int rc = r < count ? r : count - 1;
    rid_s[tid] = list[e * TOKENS + rc];
    w_s[tid] = wlist[e * TOKENS + rc];
  }
  __syncthreads();

  int wv = tid >> 6, lane = tid & 63;
  const short* arow[4];
  const short* brow[4];
  const short* We = Wt + (size_t)e * Ndim * Kdim;
  #pragma unroll
  for (int i = 0; i < 4; i++) {
    int c = wv * 4 + i;
    int rloc = c * 8 + (lane >> 3);
    size_t grow;
    if (MODE == 0) {
      grow = (size_t)rid_s[rloc] * Kdim;
    } else {
      int rr = mbase + rloc; rr = rr < count ? rr : count - 1;
      grow = (size_t)(ho + rr) * Kdim;
    }
    arow[i] = Abase + grow + (lane & 7) * 8;
    brow[i] = We + (size_t)(n0 + rloc) * Kdim + (lane & 7) * 8;
  }

  f32x4 acc[4][4] = {};
  int wr = wv >> 1, wc = wv & 1;
  int lr = lane & 15, lh = lane >> 4;

  for (int k0 = 0; k0 < Kdim; k0 += 64) {
    #pragma unroll
    for (int i = 0; i < 4; i++) {
      int c = wv * 4 + i;
      async16(&As[c * 512], arow[i] + k0);
      async16(&Bs[c * 512], brow[i] + k0);
    }
    __syncthreads();
    #pragma unroll
    for (int kk = 0; kk < 2; kk++) {
      short8v a[4], b[4];
      #pragma unroll
      for (int m = 0; m < 4; m++)
        a[m] = *(const short8v*)&As[(wr * 64 + m * 16 + lr) * 64 + kk * 32 + lh * 8];
      #pragma unroll
      for (int n = 0; n < 4; n++)
        b[n] = *(const short8v*)&Bs[(wc * 64 + n * 16 + lr) * 64 + kk * 32 + lh * 8];
      #pragma unroll
      for (int m = 0; m < 4; m++)
        #pragma unroll
        for (int n = 0; n < 4; n++)
          acc[m][n] = __builtin_amdgcn_mfma_f32_16x16x32_bf16(a[m], b[n], acc[m][n], 0, 0, 0);
    }
    __syncthreads();
  }

  // epilogue
  #pragma unroll
  for (int m = 0; m < 4; m++) {
    #pragma unroll
    for (int n = 0; n < 4; n++) {
      f32x4 v = acc[m][n];
      int colg = n0 + wc * 64 + n * 16 + lr;
      #pragma unroll
      for (int j = 0; j < 4; j++) {
        int rt = wr * 64 + m * 16 + lh * 4 + j;   // 0..127 local tile row
        int rloc = mbase + rt;
        if (rloc < count) {
          float val = v[j];
          if (MODE == 0) {
            val += bias[(size_t)e * Fm + colg];
            val = 0.5f * val * (1.f + erff(val * 0.70710678118654752f));
            Hout[(size_t)(ho + rloc) * Fm + colg] = f2b(val);
          } else {
            int tkn = rid_s[rt];
            float p = w_s[rt];
            atomicAdd(&Out[(size_t)tkn * Dm + colg], p * val);
          }
        }
      }
    }
  }
}

// ---------------- host ----------------
extern "C" void kernel_launch(void* const* d_in, const int* in_sizes, int n_in,
                              void* d_out, int out_size, void* d_ws, size_t ws_size,
                              hipStream_t stream) {
  const float* x  = (const float*)d_in[0];
  const float* rw = (const float*)d_in[1];
  const float* rb = (const float*)d_in[2];
  const float* w1 = (const float*)d_in[3];
  const float* b1 = (const float*)d_in[4];
  const float* w2 = (const float*)d_in[5];
  const float* b2 = (const float*)d_in[6];
  float* out = (float*)d_out;
  char* ws = (char*)d_ws;

  const size_t off_cnt   = 0;                     // 32 B
  const size_t off_hoffs = 32;                    // 32 B
  const size_t off_list  = 1024;                  // E*T*4 = 256 KiB
  const size_t off_wlist = off_list + (size_t)Em * TOKENS * 4;
  const size_t off_xbf   = off_wlist + (size_t)Em * TOKENS * 4;
  const size_t off_w1t   = off_xbf + (size_t)TOKENS * Dm * 2;
  const size_t off_w2t   = off_w1t + (size_t)Em * Dm * Fm * 2;
  const size_t off_h     = off_w2t + (size_t)Em * Fm * Dm * 2;
  const size_t needed    = off_h + (size_t)2 * TOKENS * Fm * 2;
  if (ws_size < needed) return;  // fail visibly (out stays poisoned)

  int*   cnt   = (int*)(ws + off_cnt);
  int*   hoffs = (int*)(ws + off_hoffs);
  int*   list  = (int*)(ws + off_list);
  float* wlist = (float*)(ws + off_wlist);
  short* xbf   = (short*)(ws + off_xbf);
  short* w1t   = (short*)(ws + off_w1t);
  short* w2t   = (short*)(ws + off_w2t);
  short* h     = (short*)(ws + off_h);

  hipMemsetAsync(cnt, 0, 32, stream);
  cvt_x_kernel<<<(TOKENS * Dm) / (256 * 8), 256, 0, stream>>>(x, xbf);
  cvt_tr_kernel<<<dim3(Fm / 64, Dm / 64, Em), 256, 0, stream>>>(w1, w1t, Dm, Fm);
  cvt_tr_kernel<<<dim3(Dm / 64, Fm / 64, Em), 256, 0, stream>>>(w2, w2t, Fm, Dm);
  router_kernel<<<TOKENS / 4, 256, 0, stream>>>(x, rw, rb, b2, out, cnt, list, wlist);
  prefix_kernel<<<1, 64, 0, stream>>>(cnt, hoffs);
  moe_gemm_kernel<0><<<dim3(Fm / 128, TOKENS / 128, Em), 256, 0, stream>>>(
      xbf, w1t, b1, h, nullptr, cnt, hoffs, list, wlist, Fm, Dm);
  moe_gemm_kernel<1><<<dim3(Dm / 128, TOKENS / 128, Em), 256, 0, stream>>>(
      h, w2t, nullptr, nullptr, out, cnt, hoffs, list, wlist, Dm, Fm);
}

// Round 4
// 503.681 us; speedup vs baseline: 1.3188x; 1.3188x over previous
//
#include <hip/hip_runtime.h>
#include <hip/hip_bf16.h>
#include <math.h>

#define TOKENS 8192
#define Dm 768
#define Fm 3072
#define Em 8
#define BM 256
#define BN 256
#define BK 64

typedef __attribute__((ext_vector_type(8))) short short8v;
typedef __attribute__((ext_vector_type(4))) float f32x4;

__device__ inline short f2b(float f) {
  __hip_bfloat16 h = __float2bfloat16(f);
  return *reinterpret_cast<short*>(&h);
}

__device__ inline void async16(short* lds, const short* g) {
  __builtin_amdgcn_global_load_lds((const __attribute__((address_space(1))) void*)g,
                                   (__attribute__((address_space(3))) void*)lds, 16, 0, 0);
}

// ------------- transpose + convert: in f32 [R][C] -> out bf16 [C][R], per expert (z) -------------
__global__ __launch_bounds__(256) void cvt_tr_kernel(const float* __restrict__ in,
                                                     short* __restrict__ out, int R, int C) {
  __shared__ short tile[64][68];
  size_t eoff = (size_t)blockIdx.z * R * C;
  const float* inp = in + eoff;
  short* outp = out + eoff;
  int tc = blockIdx.x * 64, tr = blockIdx.y * 64;
  {
    int row = threadIdx.x >> 2;
    int cch = (threadIdx.x & 3) * 16;
    const float* src = inp + (size_t)(tr + row) * C + tc + cch;
    #pragma unroll
    for (int q = 0; q < 4; q++) {
      float4 v = *(const float4*)(src + q * 4);
      tile[row][cch + q * 4 + 0] = f2b(v.x);
      tile[row][cch + q * 4 + 1] = f2b(v.y);
      tile[row][cch + q * 4 + 2] = f2b(v.z);
      tile[row][cch + q * 4 + 3] = f2b(v.w);
    }
  }
  __syncthreads();
  {
    int c = threadIdx.x >> 2;
    int rch = (threadIdx.x & 3) * 16;
    short tmp[16];
    #pragma unroll
    for (int i = 0; i < 16; i++) tmp[i] = tile[rch + i][c];
    short* dst = outp + (size_t)(tc + c) * R + tr + rch;
    *(short8v*)(dst) = *(short8v*)(tmp);
    *(short8v*)(dst + 8) = *(short8v*)(tmp + 8);
  }
}

// ---------------- router: top-2, scatter lists, meta, x->bf16 ----------------
__global__ __launch_bounds__(256) void router_kernel(
    const float* __restrict__ x, const float* __restrict__ rw,
    const float* __restrict__ rb, short* __restrict__ xb,
    int* __restrict__ cnt, int* __restrict__ list,
    int4* __restrict__ meta_i, float2* __restrict__ meta_p) {
  int wave = threadIdx.x >> 6;
  int lane = threadIdx.x & 63;
  int t = blockIdx.x * 4 + wave;
  if (t >= TOKENS) return;
  const float* xr = x + (size_t)t * Dm;
  short* xbr = xb + (size_t)t * Dm;
  float acc[Em];
  #pragma unroll
  for (int e = 0; e < Em; e++) acc[e] = 0.f;
  #pragma unroll
  for (int i = 0; i < 12; i++) {
    int d = lane + 64 * i;
    float xv = xr[d];
    xbr[d] = f2b(xv);
    const float4* rwp = (const float4*)(rw + (size_t)d * Em);
    float4 a = rwp[0], b = rwp[1];
    acc[0] += xv * a.x; acc[1] += xv * a.y; acc[2] += xv * a.z; acc[3] += xv * a.w;
    acc[4] += xv * b.x; acc[5] += xv * b.y; acc[6] += xv * b.z; acc[7] += xv * b.w;
  }
  #pragma unroll
  for (int e = 0; e < Em; e++) {
    float v = acc[e];
    #pragma unroll
    for (int s = 32; s > 0; s >>= 1) v += __shfl_xor(v, s);
    acc[e] = v + rb[e];
  }
  int i1 = 0; float m1 = acc[0];
  #pragma unroll
  for (int e = 1; e < Em; e++) if (acc[e] > m1) { m1 = acc[e]; i1 = e; }
  int i2 = -1; float m2 = -1e30f;
  #pragma unroll
  for (int e = 0; e < Em; e++) if (e != i1 && acc[e] > m2) { m2 = acc[e]; i2 = e; }
  float tt = expf(m2 - m1);
  float p0 = 1.f / (1.f + tt);
  float p1 = tt / (1.f + tt);
  if (lane == 0) {
    int s0 = atomicAdd(&cnt[i1], 1); list[i1 * TOKENS + s0] = t;
    int s1 = atomicAdd(&cnt[i2], 1); list[i2 * TOKENS + s1] = t;
    meta_i[t] = make_int4(i1, s0, i2, s1);
    meta_p[t] = make_float2(p0, p1);
  }
}

__global__ void prefix_kernel(const int* __restrict__ cnt, int* __restrict__ hoffs) {
  if (threadIdx.x == 0) {
    int s = 0;
    for (int e = 0; e < Em; e++) { hoffs[e] = s; s += cnt[e]; }
  }
}

// ---------------- grouped GEMM, 256x256 tile, dbuf + counted vmcnt + T2 swizzle ----------------
// MODE 0: h[slot] = gelu(x[tok] @ w1t^T + b1)   MODE 1: y[slot] = h[slot] @ w2t^T
template <int MODE>
__global__ __launch_bounds__(512, 2) void moe_gemm_kernel(
    const short* __restrict__ Abase, const short* __restrict__ Wt,
    const float* __restrict__ bias, short* __restrict__ Hout,
    float* __restrict__ Yout, const int* __restrict__ cnt,
    const int* __restrict__ hoffs, const int* __restrict__ list,
    int Ndim, int Kdim) {
  int e = blockIdx.z;
  int count = cnt[e];
  int mbase = blockIdx.y * BM;
  if (mbase >= count) return;
  int n0 = blockIdx.x * BN;
  int ho = hoffs[e];

  __shared__ short As[2 * BM * BK];   // 64 KiB, [slot][row][64] linear
  __shared__ short Bs[2 * BN * BK];   // 64 KiB
  __shared__ int rid_s[BM];

  int tid = threadIdx.x;
  if (MODE == 0) {
    if (tid < BM) {
      int rc = mbase + tid; if (rc > count - 1) rc = count - 1;
      rid_s[tid] = list[e * TOKENS + rc];
    }
  }
  __syncthreads();

  // ---- stage pointers (source pre-swizzled: granule ^= row&7) ----
  const short* We = Wt + (size_t)e * Ndim * Kdim;
  int swz = ((tid & 7) ^ ((tid >> 3) & 7)) * 8;
  const short* aptr[4];
  const short* bptr[4];
  #pragma unroll
  for (int q = 0; q < 4; q++) {
    int rloc = q * 64 + (tid >> 3);
    size_t grow;
    if (MODE == 0) {
      grow = (size_t)rid_s[rloc] * Kdim;
    } else {
      int rr = mbase + rloc; if (rr > count - 1) rr = count - 1;
      grow = (size_t)(ho + rr) * Kdim;
    }
    aptr[q] = Abase + grow + swz;
    bptr[q] = We + (size_t)(n0 + rloc) * Kdim + swz;
  }
  int w = tid >> 6;

  #define STAGE(s)                                              \
    {                                                           \
      _Pragma("unroll")                                         \
      for (int q = 0; q < 4; q++) {                             \
        async16(&As[(s) * (BM * BK) + q * 4096 + w * 512], aptr[q]); \
        async16(&Bs[(s) * (BN * BK) + q * 4096 + w * 512], bptr[q]); \
        aptr[q] += BK; bptr[q] += BK;                           \
      }                                                         \
    }

  int NT = Kdim / BK;
  STAGE(0);
  STAGE(1);
  asm volatile("s_waitcnt vmcnt(8)" ::: "memory");
  __builtin_amdgcn_s_barrier();

  f32x4 acc[8][4] = {};
  int lane = tid & 63;
  int wm = (tid >> 6) >> 2, wn = (tid >> 6) & 3;
  int lr = lane & 15, lh = lane >> 4;
  int rsw = lr & 7;

  for (int t = 0; t < NT; t++) {
    int s = t & 1;
    const short* Ab = &As[s * (BM * BK)];
    const short* Bb = &Bs[s * (BN * BK)];
    // kk0 fragments
    short8v a0[8], b0[4];
    #pragma unroll
    for (int m = 0; m < 8; m++)
      a0[m] = *(const short8v*)&Ab[(wm * 128 + m * 16 + lr) * 64 + ((lh ^ rsw) * 8)];
    #pragma unroll
    for (int n = 0; n < 4; n++)
      b0[n] = *(const short8v*)&Bb[(wn * 64 + n * 16 + lr) * 64 + ((lh ^ rsw) * 8)];
    __builtin_amdgcn_s_setprio(1);
    #pragma unroll
    for (int m = 0; m < 8; m++)
      #pragma unroll
      for (int n = 0; n < 4; n++)
        acc[m][n] = __builtin_amdgcn_mfma_f32_16x16x32_bf16(a0[m], b0[n], acc[m][n], 0, 0, 0);
    __builtin_amdgcn_s_setprio(0);
    // kk1 fragments
    short8v a1[8], b1v[4];
    #pragma unroll
    for (int m = 0; m < 8; m++)
      a1[m] = *(const short8v*)&Ab[(wm * 128 + m * 16 + lr) * 64 + (((4 + lh) ^ rsw) * 8)];
    #pragma unroll
    for (int n = 0; n < 4; n++)
      b1v[n] = *(const short8v*)&Bb[(wn * 64 + n * 16 + lr) * 64 + (((4 + lh) ^ rsw) * 8)];
    // all slot-s reads issued; drain mine, then barrier => all waves done reading slot s
    asm volatile("s_waitcnt lgkmcnt(0)" ::: "memory");
    __builtin_amdgcn_sched_barrier(0);
    __builtin_amdgcn_s_barrier();
    if (t + 2 < NT) STAGE(s);         // overwrite slot s with tile t+2 (safe now)
    __builtin_amdgcn_s_setprio(1);
    #pragma unroll
    for (int m = 0; m < 8; m++)
      #pragma unroll
      for (int n = 0; n < 4; n++)
        acc[m][n] = __builtin_amdgcn_mfma_f32_16x16x32_bf16(a1[m], b1v[n], acc[m][n], 0, 0, 0);
    __builtin_amdgcn_s_setprio(0);
    if (t + 2 < NT)
      asm volatile("s_waitcnt vmcnt(8)" ::: "memory");   // tile t+1's batch landed (mine)
    else
      asm volatile("s_waitcnt vmcnt(0)" ::: "memory");
    __builtin_amdgcn_s_barrier();     // all waves landed tile t+1 => safe to read next
  }

  // ---------------- epilogue ----------------
  if (MODE == 0) {
    const float* be = bias + (size_t)e * Ndim;
    #pragma unroll
    for (int m = 0; m < 8; m++) {
      #pragma unroll
      for (int j = 0; j < 4; j++) {
        int r = wm * 128 + m * 16 + lh * 4 + j;
        if (mbase + r < count) {
          size_t rowoff = (size_t)(ho + mbase + r) * Ndim;
          #pragma unroll
          for (int n = 0; n < 4; n++) {
            int colg = n0 + wn * 64 + n * 16 + lr;
            float val = acc[m][n][j] + be[colg];
            // exact-gelu via A&S 7.1.26 erf (|eps|<1.5e-7)
            float z = val * 0.70710678118654752f;
            float az = fabsf(z);
            float tt = __fdividef(1.f, fmaf(0.3275911f, az, 1.f));
            float poly = fmaf(fmaf(fmaf(fmaf(1.061405429f, tt, -1.453152027f), tt,
                              1.421413741f), tt, -0.284496736f), tt, 0.254829592f) * tt;
            float er = 1.f - poly * __expf(-az * az);
            er = z < 0.f ? -er : er;
            val = 0.5f * val * (1.f + er);
            Hout[rowoff + colg] = f2b(val);
          }
        }
      }
    }
  } else {
    #pragma unroll
    for (int m = 0; m < 8; m++) {
      #pragma unroll
      for (int j = 0; j < 4; j++) {
        int r = wm * 128 + m * 16 + lh * 4 + j;
        if (mbase + r < count) {
          float* yrow = Yout + (size_t)(ho + mbase + r) * Ndim;
          #pragma unroll
          for (int n = 0; n < 4; n++) {
            int colg = n0 + wn * 64 + n * 16 + lr;
            yrow[colg] = acc[m][n][j];
          }
        }
      }
    }
  }
  #undef STAGE
}

// ---------------- combine: out[t] = p0*(y[s0]+b2[e0]) + p1*(y[s1]+b2[e1]) ----------------
__global__ __launch_bounds__(256) void combine_kernel(
    const float* __restrict__ Y, const float* __restrict__ b2,
    const int* __restrict__ hoffs, const int4* __restrict__ meta_i,
    const float2* __restrict__ meta_p, float* __restrict__ out) {
  int wave = threadIdx.x >> 6;
  int lane = threadIdx.x & 63;
  int t = blockIdx.x * 4 + wave;
  if (t >= TOKENS) return;
  int4 mi = meta_i[t];
  float2 mp = meta_p[t];
  const float4* y0 = (const float4*)(Y + (size_t)(hoffs[mi.x] + mi.y) * Dm);
  const float4* y1 = (const float4*)(Y + (size_t)(hoffs[mi.z] + mi.w) * Dm);
  const float4* ba = (const float4*)(b2 + (size_t)mi.x * Dm);
  const float4* bb = (const float4*)(b2 + (size_t)mi.z * Dm);
  float4* orow = (float4*)(out + (size_t)t * Dm);
  #pragma unroll
  for (int i = 0; i < 3; i++) {
    int idx = lane + 64 * i;
    float4 v0 = y0[idx], v1 = y1[idx], a = ba[idx], b = bb[idx];
    float4 o;
    o.x = mp.x * (v0.x + a.x) + mp.y * (v1.x + b.x);
    o.y = mp.x * (v0.y + a.y) + mp.y * (v1.y + b.y);
    o.z = mp.x * (v0.z + a.z) + mp.y * (v1.z + b.z);
    o.w = mp.x * (v0.w + a.w) + mp.y * (v1.w + b.w);
    orow[idx] = o;
  }
}

// ---------------- host ----------------
extern "C" void kernel_launch(void* const* d_in, const int* in_sizes, int n_in,
                              void* d_out, int out_size, void* d_ws, size_t ws_size,
                              hipStream_t stream) {
  const float* x  = (const float*)d_in[0];
  const float* rw = (const float*)d_in[1];
  const float* rb = (const float*)d_in[2];
  const float* w1 = (const float*)d_in[3];
  const float* b1 = (const float*)d_in[4];
  const float* w2 = (const float*)d_in[5];
  const float* b2 = (const float*)d_in[6];
  float* out = (float*)d_out;
  char* ws = (char*)d_ws;

  const size_t off_cnt    = 0;
  const size_t off_hoffs  = 64;
  const size_t off_list   = 1024;                                   // E*T*4 = 256K
  const size_t off_meta_i = off_list + (size_t)Em * TOKENS * 4;     // 128K
  const size_t off_meta_p = off_meta_i + (size_t)TOKENS * 16;       // 64K
  const size_t off_xbf    = off_meta_p + (size_t)TOKENS * 8;
  const size_t off_w1t    = off_xbf + (size_t)TOKENS * Dm * 2;      // 12.6M
  const size_t off_w2t    = off_w1t + (size_t)Em * Dm * Fm * 2;     // +37.7M
  const size_t off_h      = off_w2t + (size_t)Em * Fm * Dm * 2;     // +37.7M
  const size_t needed     = off_h + (size_t)2 * TOKENS * Fm * 2;    // +100.7M
  if (ws_size < needed) return;

  int*    cnt    = (int*)(ws + off_cnt);
  int*    hoffs  = (int*)(ws + off_hoffs);
  int*    list   = (int*)(ws + off_list);
  int4*   meta_i = (int4*)(ws + off_meta_i);
  float2* meta_p = (float2*)(ws + off_meta_p);
  short*  xbf    = (short*)(ws + off_xbf);
  short*  w1t    = (short*)(ws + off_w1t);
  short*  w2t    = (short*)(ws + off_w2t);
  short*  h      = (short*)(ws + off_h);
  // y (16384 x 768 f32 = 50.33MB) aliases xbf+w1t (dead after GEMM1) — exact fit
  float*  y      = (float*)(ws + off_xbf);

  hipMemsetAsync(cnt, 0, 32, stream);
  cvt_tr_kernel<<<dim3(Fm / 64, Dm / 64, Em), 256, 0, stream>>>(w1, w1t, Dm, Fm);
  cvt_tr_kernel<<<dim3(Dm / 64, Fm / 64, Em), 256, 0, stream>>>(w2, w2t, Fm, Dm);
  router_kernel<<<TOKENS / 4, 256, 0, stream>>>(x, rw, rb, xbf, cnt, list, meta_i, meta_p);
  prefix_kernel<<<1, 64, 0, stream>>>(cnt, hoffs);
  moe_gemm_kernel<0><<<dim3(Fm / BN, TOKENS / BM, Em), 512, 0, stream>>>(
      xbf, w1t, b1, h, nullptr, cnt, hoffs, list, Fm, Dm);
  moe_gemm_kernel<1><<<dim3(Dm / BN, TOKENS / BM, Em), 512, 0, stream>>>(
      h, w2t, nullptr, nullptr, y, cnt, hoffs, list, Dm, Fm);
  combine_kernel<<<TOKENS / 4, 256, 0, stream>>>(y, b2, hoffs, meta_i, meta_p, out);
}

// Round 6
// 337.071 us; speedup vs baseline: 1.9707x; 1.4943x over previous
//
#include <hip/hip_runtime.h>
#include <hip/hip_bf16.h>
#include <math.h>

#define TOKENS 8192
#define Dm 768
#define Fm 3072
#define Em 8
#define BM 256
#define BN 256
#define BK 64

typedef __attribute__((ext_vector_type(8))) short short8v;
typedef __attribute__((ext_vector_type(4))) short short4v;
typedef __attribute__((ext_vector_type(4))) float f32x4;

__device__ inline short f2b(float f) {
  __hip_bfloat16 h = __float2bfloat16(f);
  return *reinterpret_cast<short*>(&h);
}

__device__ inline void async16(short* lds, const short* g) {
  __builtin_amdgcn_global_load_lds((const __attribute__((address_space(1))) void*)g,
                                   (__attribute__((address_space(3))) void*)lds, 16, 0, 0);
}

// ------------- transpose + convert: in f32 [R][C] -> out bf16 [C][R], per expert (z) -------------
__global__ __launch_bounds__(256) void cvt_tr_kernel(const float* __restrict__ in,
                                                     short* __restrict__ out, int R, int C) {
  __shared__ short tile[64][68];
  size_t eoff = (size_t)blockIdx.z * R * C;
  const float* inp = in + eoff;
  short* outp = out + eoff;
  int tc = blockIdx.x * 64, tr = blockIdx.y * 64;
  {
    int row = threadIdx.x >> 2;
    int cch = (threadIdx.x & 3) * 16;
    const float* src = inp + (size_t)(tr + row) * C + tc + cch;
    #pragma unroll
    for (int q = 0; q < 4; q++) {
      float4 v = *(const float4*)(src + q * 4);
      tile[row][cch + q * 4 + 0] = f2b(v.x);
      tile[row][cch + q * 4 + 1] = f2b(v.y);
      tile[row][cch + q * 4 + 2] = f2b(v.z);
      tile[row][cch + q * 4 + 3] = f2b(v.w);
    }
  }
  __syncthreads();
  {
    int c = threadIdx.x >> 2;
    int rch = (threadIdx.x & 3) * 16;
    short tmp[16];
    #pragma unroll
    for (int i = 0; i < 16; i++) tmp[i] = tile[rch + i][c];
    short* dst = outp + (size_t)(tc + c) * R + tr + rch;
    *(short8v*)(dst) = *(short8v*)(tmp);
    *(short8v*)(dst + 8) = *(short8v*)(tmp + 8);
  }
}

// ---------------- router: top-2 per token + x->bf16; NO atomics ----------------
__global__ __launch_bounds__(256) void router_kernel(
    const float* __restrict__ x, const float* __restrict__ rw,
    const float* __restrict__ rb, short* __restrict__ xb,
    int2* __restrict__ meta_e, float2* __restrict__ meta_p) {
  int wave = threadIdx.x >> 6;
  int lane = threadIdx.x & 63;
  int t = blockIdx.x * 4 + wave;
  if (t >= TOKENS) return;
  const float* xr = x + (size_t)t * Dm;
  short* xbr = xb + (size_t)t * Dm;
  float acc[Em];
  #pragma unroll
  for (int e = 0; e < Em; e++) acc[e] = 0.f;
  #pragma unroll
  for (int i = 0; i < 3; i++) {
    int d = i * 256 + lane * 4;
    float4 v = *(const float4*)(xr + d);
    short4v s;
    s[0] = f2b(v.x); s[1] = f2b(v.y); s[2] = f2b(v.z); s[3] = f2b(v.w);
    *(short4v*)(xbr + d) = s;
    #pragma unroll
    for (int j = 0; j < 4; j++) {
      float xv = (j == 0) ? v.x : (j == 1) ? v.y : (j == 2) ? v.z : v.w;
      const float4* rwp = (const float4*)(rw + (size_t)(d + j) * Em);
      float4 a = rwp[0], b = rwp[1];
      acc[0] += xv * a.x; acc[1] += xv * a.y; acc[2] += xv * a.z; acc[3] += xv * a.w;
      acc[4] += xv * b.x; acc[5] += xv * b.y; acc[6] += xv * b.z; acc[7] += xv * b.w;
    }
  }
  #pragma unroll
  for (int e = 0; e < Em; e++) {
    float v = acc[e];
    #pragma unroll
    for (int s = 32; s > 0; s >>= 1) v += __shfl_xor(v, s);
    acc[e] = v + rb[e];
  }
  int i1 = 0; float m1 = acc[0];
  #pragma unroll
  for (int e = 1; e < Em; e++) if (acc[e] > m1) { m1 = acc[e]; i1 = e; }
  int i2 = -1; float m2 = -1e30f;
  #pragma unroll
  for (int e = 0; e < Em; e++) if (e != i1 && acc[e] > m2) { m2 = acc[e]; i2 = e; }
  float tt = expf(m2 - m1);
  float p0 = 1.f / (1.f + tt);
  float p1 = tt / (1.f + tt);
  if (lane == 0) {
    meta_e[t] = make_int2(i1, i2);
    meta_p[t] = make_float2(p0, p1);
  }
}

// ---------------- scatter: hierarchical (LDS ranks + 8 global atomics/block) ----------------
__global__ __launch_bounds__(256) void scatter_kernel(
    const int2* __restrict__ meta_e, int* __restrict__ cnt,
    int* __restrict__ list, int4* __restrict__ meta_i) {
  __shared__ int lcnt[Em];
  __shared__ int gbase[Em];
  int t = blockIdx.x * 256 + threadIdx.x;
  if (threadIdx.x < Em) lcnt[threadIdx.x] = 0;
  __syncthreads();
  int2 e = meta_e[t];
  int r0 = atomicAdd(&lcnt[e.x], 1);
  int r1 = atomicAdd(&lcnt[e.y], 1);
  __syncthreads();
  if (threadIdx.x < Em) gbase[threadIdx.x] = atomicAdd(&cnt[threadIdx.x], lcnt[threadIdx.x]);
  __syncthreads();
  int s0 = gbase[e.x] + r0;
  int s1 = gbase[e.y] + r1;
  list[e.x * TOKENS + s0] = t;
  list[e.y * TOKENS + s1] = t;
  meta_i[t] = make_int4(e.x, s0, e.y, s1);
}

__global__ void prefix_kernel(const int* __restrict__ cnt, int* __restrict__ hoffs) {
  if (threadIdx.x == 0) {
    int s = 0;
    for (int e = 0; e < Em; e++) { hoffs[e] = s; s += cnt[e]; }
  }
}

// ---------------- grouped GEMM, 256x256 tile, dbuf + counted vmcnt + T2 swizzle ----------------
// MODE 0: h[slot] = gelu(x[tok] @ w1t^T + b1)   MODE 1: y[slot] = h[slot] @ w2t^T
template <int MODE>
__global__ __launch_bounds__(512, 2) void moe_gemm_kernel(
    const short* __restrict__ Abase, const short* __restrict__ Wt,
    const float* __restrict__ bias, short* __restrict__ Hout,
    float* __restrict__ Yout, const int* __restrict__ cnt,
    const int* __restrict__ hoffs, const int* __restrict__ list,
    int Ndim, int Kdim) {
  int e = blockIdx.z;
  int count = cnt[e];
  int mbase = blockIdx.y * BM;
  if (mbase >= count) return;
  int n0 = blockIdx.x * BN;
  int ho = hoffs[e];

  __shared__ short As[2 * BM * BK];   // 64 KiB, [slot][row][64] linear
  __shared__ short Bs[2 * BN * BK];   // 64 KiB
  __shared__ int rid_s[BM];

  int tid = threadIdx.x;
  if (MODE == 0) {
    if (tid < BM) {
      int rc = mbase + tid; if (rc > count - 1) rc = count - 1;
      rid_s[tid] = list[e * TOKENS + rc];
    }
  }
  __syncthreads();

  // ---- stage pointers (source pre-swizzled: granule ^= row&7) ----
  const short* We = Wt + (size_t)e * Ndim * Kdim;
  int swz = ((tid & 7) ^ ((tid >> 3) & 7)) * 8;
  const short* aptr[4];
  const short* bptr[4];
  #pragma unroll
  for (int q = 0; q < 4; q++) {
    int rloc = q * 64 + (tid >> 3);
    size_t grow;
    if (MODE == 0) {
      grow = (size_t)rid_s[rloc] * Kdim;
    } else {
      int rr = mbase + rloc; if (rr > count - 1) rr = count - 1;
      grow = (size_t)(ho + rr) * Kdim;
    }
    aptr[q] = Abase + grow + swz;
    bptr[q] = We + (size_t)(n0 + rloc) * Kdim + swz;
  }
  int w = tid >> 6;

  #define STAGE(s)                                              \
    {                                                           \
      _Pragma("unroll")                                         \
      for (int q = 0; q < 4; q++) {                             \
        async16(&As[(s) * (BM * BK) + q * 4096 + w * 512], aptr[q]); \
        async16(&Bs[(s) * (BN * BK) + q * 4096 + w * 512], bptr[q]); \
        aptr[q] += BK; bptr[q] += BK;                           \
      }                                                         \
    }

  int NT = Kdim / BK;
  STAGE(0);
  STAGE(1);
  asm volatile("s_waitcnt vmcnt(8)" ::: "memory");
  __builtin_amdgcn_s_barrier();

  f32x4 acc[8][4] = {};
  int lane = tid & 63;
  int wm = (tid >> 6) >> 2, wn = (tid >> 6) & 3;
  int lr = lane & 15, lh = lane >> 4;
  int rsw = lr & 7;

  for (int t = 0; t < NT; t++) {
    int s = t & 1;
    const short* Ab = &As[s * (BM * BK)];
    const short* Bb = &Bs[s * (BN * BK)];
    // kk0 fragments
    short8v a0[8], b0[4];
    #pragma unroll
    for (int m = 0; m < 8; m++)
      a0[m] = *(const short8v*)&Ab[(wm * 128 + m * 16 + lr) * 64 + ((lh ^ rsw) * 8)];
    #pragma unroll
    for (int n = 0; n < 4; n++)
      b0[n] = *(const short8v*)&Bb[(wn * 64 + n * 16 + lr) * 64 + ((lh ^ rsw) * 8)];
    __builtin_amdgcn_s_setprio(1);
    #pragma unroll
    for (int m = 0; m < 8; m++)
      #pragma unroll
      for (int n = 0; n < 4; n++)
        acc[m][n] = __builtin_amdgcn_mfma_f32_16x16x32_bf16(a0[m], b0[n], acc[m][n], 0, 0, 0);
    __builtin_amdgcn_s_setprio(0);
    // kk1 fragments
    short8v a1[8], b1v[4];
    #pragma unroll
    for (int m = 0; m < 8; m++)
      a1[m] = *(const short8v*)&Ab[(wm * 128 + m * 16 + lr) * 64 + (((4 + lh) ^ rsw) * 8)];
    #pragma unroll
    for (int n = 0; n < 4; n++)
      b1v[n] = *(const short8v*)&Bb[(wn * 64 + n * 16 + lr) * 64 + (((4 + lh) ^ rsw) * 8)];
    // all slot-s reads issued; drain mine, then barrier => all waves done reading slot s
    asm volatile("s_waitcnt lgkmcnt(0)" ::: "memory");
    __builtin_amdgcn_sched_barrier(0);
    __builtin_amdgcn_s_barrier();
    if (t + 2 < NT) STAGE(s);         // overwrite slot s with tile t+2 (safe now)
    __builtin_amdgcn_s_setprio(1);
    #pragma unroll
    for (int m = 0; m < 8; m++)
      #pragma unroll
      for (int n = 0; n < 4; n++)
        acc[m][n] = __builtin_amdgcn_mfma_f32_16x16x32_bf16(a1[m], b1v[n], acc[m][n], 0, 0, 0);
    __builtin_amdgcn_s_setprio(0);
    if (t + 2 < NT)
      asm volatile("s_waitcnt vmcnt(8)" ::: "memory");   // tile t+1's batch landed (mine)
    else
      asm volatile("s_waitcnt vmcnt(0)" ::: "memory");
    __builtin_amdgcn_s_barrier();     // all waves landed tile t+1 => safe to read next
  }

  // ---------------- epilogue ----------------
  if (MODE == 0) {
    const float* be = bias + (size_t)e * Ndim;
    #pragma unroll
    for (int m = 0; m < 8; m++) {
      #pragma unroll
      for (int j = 0; j < 4; j++) {
        int r = wm * 128 + m * 16 + lh * 4 + j;
        if (mbase + r < count) {
          size_t rowoff = (size_t)(ho + mbase + r) * Ndim;
          #pragma unroll
          for (int n = 0; n < 4; n++) {
            int colg = n0 + wn * 64 + n * 16 + lr;
            float val = acc[m][n][j] + be[colg];
            // exact-gelu via A&S 7.1.26 erf (|eps|<1.5e-7)
            float z = val * 0.70710678118654752f;
            float az = fabsf(z);
            float tt = __fdividef(1.f, fmaf(0.3275911f, az, 1.f));
            float poly = fmaf(fmaf(fmaf(fmaf(1.061405429f, tt, -1.453152027f), tt,
                              1.421413741f), tt, -0.284496736f), tt, 0.254829592f) * tt;
            float er = 1.f - poly * __expf(-az * az);
            er = z < 0.f ? -er : er;
            val = 0.5f * val * (1.f + er);
            Hout[rowoff + colg] = f2b(val);
          }
        }
      }
    }
  } else {
    #pragma unroll
    for (int m = 0; m < 8; m++) {
      #pragma unroll
      for (int j = 0; j < 4; j++) {
        int r = wm * 128 + m * 16 + lh * 4 + j;
        if (mbase + r < count) {
          float* yrow = Yout + (size_t)(ho + mbase + r) * Ndim;
          #pragma unroll
          for (int n = 0; n < 4; n++) {
            int colg = n0 + wn * 64 + n * 16 + lr;
            yrow[colg] = acc[m][n][j];
          }
        }
      }
    }
  }
  #undef STAGE
}

// ---------------- combine: out[t] = p0*(y[s0]+b2[e0]) + p1*(y[s1]+b2[e1]) ----------------
__global__ __launch_bounds__(256) void combine_kernel(
    const float* __restrict__ Y, const float* __restrict__ b2,
    const int* __restrict__ hoffs, const int4* __restrict__ meta_i,
    const float2* __restrict__ meta_p, float* __restrict__ out) {
  int wave = threadIdx.x >> 6;
  int lane = threadIdx.x & 63;
  int t = blockIdx.x * 4 + wave;
  if (t >= TOKENS) return;
  int4 mi = meta_i[t];
  float2 mp = meta_p[t];
  const float4* y0 = (const float4*)(Y + (size_t)(hoffs[mi.x] + mi.y) * Dm);
  const float4* y1 = (const float4*)(Y + (size_t)(hoffs[mi.z] + mi.w) * Dm);
  const float4* ba = (const float4*)(b2 + (size_t)mi.x * Dm);
  const float4* bb = (const float4*)(b2 + (size_t)mi.z * Dm);
  float4* orow = (float4*)(out + (size_t)t * Dm);
  #pragma unroll
  for (int i = 0; i < 3; i++) {
    int idx = lane + 64 * i;
    float4 v0 = y0[idx], v1 = y1[idx], a = ba[idx], b = bb[idx];
    float4 o;
    o.x = mp.x * (v0.x + a.x) + mp.y * (v1.x + b.x);
    o.y = mp.x * (v0.y + a.y) + mp.y * (v1.y + b.y);
    o.z = mp.x * (v0.z + a.z) + mp.y * (v1.z + b.z);
    o.w = mp.x * (v0.w + a.w) + mp.y * (v1.w + b.w);
    orow[idx] = o;
  }
}

// ---------------- host ----------------
extern "C" void kernel_launch(void* const* d_in, const int* in_sizes, int n_in,
                              void* d_out, int out_size, void* d_ws, size_t ws_size,
                              hipStream_t stream) {
  const float* x  = (const float*)d_in[0];
  const float* rw = (const float*)d_in[1];
  const float* rb = (const float*)d_in[2];
  const float* w1 = (const float*)d_in[3];
  const float* b1 = (const float*)d_in[4];
  const float* w2 = (const float*)d_in[5];
  const float* b2 = (const float*)d_in[6];
  float* out = (float*)d_out;
  char* ws = (char*)d_ws;

  const size_t off_cnt    = 0;
  const size_t off_hoffs  = 64;
  const size_t off_list   = 1024;                                   // E*T*4 = 256K
  const size_t off_meta_i = off_list + (size_t)Em * TOKENS * 4;     // 128K
  const size_t off_meta_p = off_meta_i + (size_t)TOKENS * 16;       // 64K
  const size_t off_meta_e = off_meta_p + (size_t)TOKENS * 8;        // 64K
  const size_t off_xbf    = off_meta_e + (size_t)TOKENS * 8;
  const size_t off_w1t    = off_xbf + (size_t)TOKENS * Dm * 2;      // 12.6M
  const size_t off_w2t    = off_w1t + (size_t)Em * Dm * Fm * 2;     // +37.7M
  const size_t off_h      = off_w2t + (size_t)Em * Fm * Dm * 2;     // +37.7M
  const size_t needed     = off_h + (size_t)2 * TOKENS * Fm * 2;    // +100.7M
  if (ws_size < needed) return;

  int*    cnt    = (int*)(ws + off_cnt);
  int*    hoffs  = (int*)(ws + off_hoffs);
  int*    list   = (int*)(ws + off_list);
  int4*   meta_i = (int4*)(ws + off_meta_i);
  float2* meta_p = (float2*)(ws + off_meta_p);
  int2*   meta_e = (int2*)(ws + off_meta_e);
  short*  xbf    = (short*)(ws + off_xbf);
  short*  w1t    = (short*)(ws + off_w1t);
  short*  w2t    = (short*)(ws + off_w2t);
  short*  h      = (short*)(ws + off_h);
  // y (16384 x 768 f32 = 50.33MB) aliases xbf+w1t (dead after GEMM1) — exact fit
  float*  y      = (float*)(ws + off_xbf);

  hipMemsetAsync(cnt, 0, 32, stream);
  cvt_tr_kernel<<<dim3(Fm / 64, Dm / 64, Em), 256, 0, stream>>>(w1, w1t, Dm, Fm);
  cvt_tr_kernel<<<dim3(Dm / 64, Fm / 64, Em), 256, 0, stream>>>(w2, w2t, Fm, Dm);
  router_kernel<<<TOKENS / 4, 256, 0, stream>>>(x, rw, rb, xbf, meta_e, meta_p);
  scatter_kernel<<<TOKENS / 256, 256, 0, stream>>>(meta_e, cnt, list, meta_i);
  prefix_kernel<<<1, 64, 0, stream>>>(cnt, hoffs);
  moe_gemm_kernel<0><<<dim3(Fm / BN, TOKENS / BM, Em), 512, 0, stream>>>(
      xbf, w1t, b1, h, nullptr, cnt, hoffs, list, Fm, Dm);
  moe_gemm_kernel<1><<<dim3(Dm / BN, TOKENS / BM, Em), 512, 0, stream>>>(
      h, w2t, nullptr, nullptr, y, cnt, hoffs, list, Dm, Fm);
  combine_kernel<<<TOKENS / 4, 256, 0, stream>>>(y, b2, hoffs, meta_i, meta_p, out);
}